// Round 1
// baseline (409.228 us; speedup 1.0000x reference)
//
#include <hip/hip_runtime.h>
#include <hip/hip_bf16.h>

// X-gate on qubit 6 of a 13-qubit state: (x @ op)[r][j] = x[r][j ^ 64].
// op = I(64) kron X kron I(64) is a permutation matrix -> pure memory shuffle.
// In float4 units (4 floats), XOR 64 floats == XOR 16 float4s (64-aligned
// chunks contain whole float4s), so: out4[i] = in4[i ^ 16].

#define N4_PER_INPUT (2048ull * 8192ull / 4ull)   // 4,194,304 float4 per input

__global__ __launch_bounds__(256) void xgate_perm_kernel(
    const float4* __restrict__ x0,
    const float4* __restrict__ x1,
    float4* __restrict__ out)
{
    const size_t total = 2ull * N4_PER_INPUT;           // 8,388,608
    size_t i = (size_t)blockIdx.x * blockDim.x + threadIdx.x;
    const size_t stride = (size_t)gridDim.x * blockDim.x;
    for (; i < total; i += stride) {
        // first half of out <- x0, second half <- x1 (tuple concat order)
        const float4* base = (i < N4_PER_INPUT) ? x0 : x1;
        const size_t local = (i & (N4_PER_INPUT - 1)) ^ 16;  // flip bit 6 of float idx
        out[i] = base[local];
    }
}

extern "C" void kernel_launch(void* const* d_in, const int* in_sizes, int n_in,
                              void* d_out, int out_size, void* d_ws, size_t ws_size,
                              hipStream_t stream) {
    const float4* x0 = (const float4*)d_in[0];
    const float4* x1 = (const float4*)d_in[1];
    // d_in[2] is the 8192x8192 op matrix -- provably a bit-6 permutation; unused.
    float4* out = (float4*)d_out;

    // 8,388,608 float4 elements total; 16384 blocks x 256 threads -> 2 elems/thread.
    const int threads = 256;
    const int blocks  = 16384;
    xgate_perm_kernel<<<blocks, threads, 0, stream>>>(x0, x1, out);
}

// Round 3
// 397.804 us; speedup vs baseline: 1.0287x; 1.0287x over previous
//
#include <hip/hip_runtime.h>
#include <hip/hip_bf16.h>

// X-gate on qubit 6 of a 13-qubit state: (x @ op)[r][j] = x[r][j ^ 64].
// op = I(64) kron X kron I(64) is a permutation matrix -> pure memory shuffle.
// In float4 units: out4[i] = in4[i ^ 16]  (flip bit 4 of the float4 index).
//
// Round-3: same as round-2 plan, but use a Clang ext_vector_type for the 16 B
// vector -- __builtin_nontemporal_{load,store} rejects HIP_vector_type structs.

typedef __attribute__((ext_vector_type(4))) float f32x4;

#define N4_PER_INPUT (2048ull * 8192ull / 4ull)   // 4,194,304 float4 per input

__global__ __launch_bounds__(256) void xgate_perm_kernel(
    const f32x4* __restrict__ x0,
    const f32x4* __restrict__ x1,
    f32x4* __restrict__ out)
{
    // gridDim.x = 8192: blocks [0,4096) -> x0, [4096,8192) -> x1.
    const unsigned b          = blockIdx.x;
    const unsigned halfBlocks = gridDim.x >> 1;          // 4096
    const bool     second     = (b >= halfBlocks);       // wave-uniform

    const f32x4* __restrict__ src = second ? x1 : x0;
    f32x4* __restrict__       dst = out + (second ? N4_PER_INPUT : 0);

    // Each block covers 1024 consecutive float4 (16 KiB); each thread does 4,
    // strided by 256 so every wave's 64 lanes stay contiguous (fully coalesced;
    // ^16 permutes whole 32-element groups inside the covered range).
    const size_t base = (size_t)(b & (halfBlocks - 1)) * 1024u + threadIdx.x;

#pragma unroll
    for (int k = 0; k < 4; ++k) {
        const size_t idx = base + (size_t)k * 256u;
        f32x4 v = __builtin_nontemporal_load(&src[idx ^ 16]);
        __builtin_nontemporal_store(v, &dst[idx]);
    }
}

extern "C" void kernel_launch(void* const* d_in, const int* in_sizes, int n_in,
                              void* d_out, int out_size, void* d_ws, size_t ws_size,
                              hipStream_t stream) {
    const f32x4* x0 = (const f32x4*)d_in[0];
    const f32x4* x1 = (const f32x4*)d_in[1];
    // d_in[2] is the 8192x8192 op matrix -- provably a bit-6 permutation; unused.
    f32x4* out = (f32x4*)d_out;

    // 8,388,608 float4 total / (4 per thread) / 256 threads = 8192 blocks.
    xgate_perm_kernel<<<8192, 256, 0, stream>>>(x0, x1, out);
}